// Round 12
// baseline (426.825 us; speedup 1.0000x reference)
//
#include <hip/hip_runtime.h>
#include <hip/hip_bf16.h>
#include <cstdint>

#define BATCH 64
#define CIN 3
#define IMG 384
#define PATCH 16
#define HID 768
#define CQ 96
#define HW24 24
#define NP 576
#define MROWS (BATCH*NP)   /* 36864 */
#define KDIM 768
#define NVQK 1024          /* V(768) + Q(96) + K(96) + pad(64) */
#define NT_K 12            /* 768 / 64 K-tiles */
#define NEGINF (-1e30f)

typedef __attribute__((ext_vector_type(8))) short s16x8;
typedef __attribute__((ext_vector_type(4))) float f32x4;

__device__ __forceinline__ float bf2f(unsigned short u) {
    union { unsigned int i; float f; } x; x.i = ((unsigned int)u) << 16; return x.f;
}
__device__ __forceinline__ unsigned short f2bf(float f) {
    union { float f; unsigned int i; } x; x.f = f;
    unsigned int r = x.i + 0x7fffu + ((x.i >> 16) & 1u);
    return (unsigned short)(r >> 16);
}
__device__ __forceinline__ unsigned int f2bf2(float a, float b) {
    union { __hip_bfloat162 h; unsigned int u; } c;
    c.h = __float22bfloat162_rn(make_float2(a, b));
    return c.u;
}

__device__ __forceinline__ void gload_lds16(const void* g, void* l) {
    __builtin_amdgcn_global_load_lds(
        (const __attribute__((address_space(1))) void*)(uintptr_t)g,
        (__attribute__((address_space(3))) void*)(uint32_t)(uintptr_t)l,
        16, 0, 0);
}

// K-packed matrix layout: [mt256][kt][256][64]
__device__ __forceinline__ size_t kp_addr(int row, int col) {
    return (((size_t)(row >> 8) * NT_K + (col >> 6)) * 256 + (row & 255)) * 64 + (col & 63);
}

// ---------------- weight prep ----------------
__global__ void k_prep(const float* __restrict__ pw, const float* __restrict__ wq,
                       const float* __restrict__ wk, const float* __restrict__ wv,
                       const float* __restrict__ bq, const float* __restrict__ bk,
                       const float* __restrict__ bv,
                       unsigned short* __restrict__ Wp, unsigned short* __restrict__ Wvqk,
                       float* __restrict__ Bvqk) {
    int t = blockIdx.x * 256 + threadIdx.x;
    if (t < HID * HID) Wp[t] = f2bf(pw[t]);
    if (t < NVQK * HID) {
        int row = t / HID; int col = t - row * HID;
        float val = 0.f;
        if (row < 768) val = wv[t];
        else if (row < 864) val = wq[(row - 768) * HID + col];
        else if (row < 960) val = wk[(row - 864) * HID + col];
        Wvqk[t] = f2bf(val);
    }
    if (t < NVQK) {
        float v = 0.f;
        if (t < 768) v = bv[t]; else if (t < 864) v = bq[t - 768]; else if (t < 960) v = bk[t - 864];
        Bvqk[t] = v;
    }
}

__device__ __forceinline__ void stageB_half(const unsigned short* __restrict__ gmat,
        int growbase, char* ldsregion, int kcol, int rl, int sp, int ldsoff0) {
    const unsigned short* g0 = gmat + (size_t)(growbase + rl) * KDIM + kcol + sp * 8;
    gload_lds16(g0, ldsregion + ldsoff0);
    gload_lds16(g0 + (size_t)8 * KDIM, ldsregion + ldsoff0 + 1024);
}

// ============ FUSED im2col + 256x384x64 bf16 GEMM (wide-N, port-byte-minimal) ============
// 1024 threads = 16 waves (4M x 4N); per wave 64x96 (acc[4][6]). Grid 288 = 144 A-tiles x 2 N-halves
// -> x pulled through ports by only 2 sibling blocks (~113MB once via L2); B panel 590KB/block.
// LDS 160KB: A dbuf 2x32K @0/32K, B dbuf 2x48K @64K/112K. Round-8 proven schedule:
// issue t+1 loads at top, vmcnt(0)+writeA+lgkmcnt(0)+barrier at boundary.
// gamma==0: epilogue writes f32 out = acc+bias+pos (final). gamma!=0: Y (K-packed bf16).
__global__ __launch_bounds__(1024, 1) void k_gemmFused(
    const float* __restrict__ x, const unsigned short* __restrict__ Bw,
    const float* __restrict__ bias, unsigned short* __restrict__ Y,
    float* __restrict__ outF, const float* __restrict__ pos,
    const float* __restrict__ gamma)
{
    extern __shared__ char smem[];
    const int tid  = threadIdx.x;
    const int lane = tid & 63;
    const int w    = tid >> 6;   // 0..15
    const int wm   = w >> 2;     // 0..3 -> 64-row quarter
    const int wn   = w & 3;      // 0..3 -> 96-col quarter

    // XCD chunk swizzle (288 % 8 == 0), A-tile-major: 2 N-siblings adjacent -> x panel L2-shared
    const int chunk = gridDim.x >> 3;
    const int bs = (blockIdx.x & 7) * chunk + (blockIdx.x >> 3);
    const int bx = bs >> 1, by = bs & 1;
    const int blockN = by * 384;

    // B staging constants: 1024 thr x 3 slots cover 384 rows x 8 slots; sp j-invariant
    const int rb_  = tid >> 3;                       // base row 0..127 (rows rb_, rb_+128, rb_+256)
    const int sp   = (tid & 7) ^ (rb_ & 7);          // pre-swizzled source slot
    const int ldsoffB = tid << 4;

    // ds_read constants (byte ^= (row&7)<<4 within 128B row)
    const int lx   = (lane & 15) << 7;
    const int swz  = (lane & 7) << 4;
    const int cbx0 = (((lane >> 4) << 4)) ^ swz;
    const int cbx1 = (64 + ((lane >> 4) << 4)) ^ swz;

    // A staging: thread -> row rr (0..255), k-quarter q (one 16-float contiguous image row)
    const int rr = tid >> 2;
    const int q  = tid & 3;
    const int grow = (bx << 8) + rr;
    const int b  = grow / NP;
    const int p  = grow - b * NP;
    const int ph = p / HW24, pw = p - ph * HW24;
    const float* xrow = x + (size_t)b * (CIN * IMG * IMG) + ph * (PATCH * IMG) + pw * PATCH;
    const int swzr  = (rr & 7) << 4;
    const int wbase = rr * 128;

    char* paC = smem;             // A(t)   32K  [256][128B]
    char* paN = smem + 32768;     // A(t+1) write target
    char* pbC = smem + 65536;     // B(t)   48K  [384][128B]
    char* pbN = smem + 114688;    // B(t+1) stage target

    float4 ld[4];   // one 16-float image row (plain by-capture; r9 lesson)
    auto loadA = [&](int t) {
        const int kk = 4 * t + q;                    // 0..47 -> (c = kk>>4, i = kk&15)
        const float* src = xrow + (kk >> 4) * (IMG * IMG) + (kk & 15) * IMG;
        #pragma unroll
        for (int u = 0; u < 4; ++u) ld[u] = *(const float4*)(src + 4 * u);
    };
    auto writeA = [&](char* dst) {
        #pragma unroll
        for (int u = 0; u < 2; ++u) {
            int4 pk;
            pk.x = f2bf2(ld[2 * u].x,     ld[2 * u].y);
            pk.y = f2bf2(ld[2 * u].z,     ld[2 * u].w);
            pk.z = f2bf2(ld[2 * u + 1].x, ld[2 * u + 1].y);
            pk.w = f2bf2(ld[2 * u + 1].z, ld[2 * u + 1].w);
            *reinterpret_cast<int4*>(dst + wbase + (((q << 5) + (u << 4)) ^ swzr)) = pk;
        }
    };
    auto stageB = [&](char* dst, int kcol) {
        const unsigned short* g0 = Bw + (size_t)(blockN + rb_) * KDIM + kcol + sp * 8;
        gload_lds16(g0,                      dst + ldsoffB);            // rows rb_
        gload_lds16(g0 + (size_t)128 * KDIM, dst + ldsoffB + 16384);    // rb_+128
        gload_lds16(g0 + (size_t)256 * KDIM, dst + ldsoffB + 32768);    // rb_+256
    };

    f32x4 acc[4][6] = {};

    // prologue: A(0)->regs, B(0)->pbC, write A(0), issue A(1)
    loadA(0);            // 4 VMEM (oldest)
    stageB(pbC, 0);      // 3 VMEM
    asm volatile("s_waitcnt vmcnt(3)" ::: "memory");   // x(0) landed
    __builtin_amdgcn_sched_barrier(0);
    writeA(paC);
    loadA(1);            // 4 VMEM in flight
    asm volatile("s_waitcnt vmcnt(4)" ::: "memory");   // B(0) landed; x(1) flying
    asm volatile("s_waitcnt lgkmcnt(0)" ::: "memory");
    __builtin_amdgcn_sched_barrier(0);
    __builtin_amdgcn_s_barrier();

    #pragma unroll 1
    for (int t = 0; t < NT_K; ++t) {
        if (t + 1 < NT_K) stageB(pbN, (t + 1) << 6);   // 3 VMEM (x(t+1) already flying)
        // fragments
        s16x8 af[4][2];
        #pragma unroll
        for (int m = 0; m < 4; ++m) {
            const int rb0 = wm * 8192 + m * 2048 + lx;
            af[m][0] = *(const s16x8*)(paC + rb0 + cbx0);
            af[m][1] = *(const s16x8*)(paC + rb0 + cbx1);
        }
        __builtin_amdgcn_s_setprio(1);
        #pragma unroll
        for (int nf = 0; nf < 6; ++nf) {
            const int rb = wn * 12288 + nf * 2048 + lx;
            s16x8 b0 = *(const s16x8*)(pbC + rb + cbx0);
            s16x8 b1 = *(const s16x8*)(pbC + rb + cbx1);
            #pragma unroll
            for (int m = 0; m < 4; ++m)
                acc[m][nf] = __builtin_amdgcn_mfma_f32_16x16x32_bf16(b0, af[m][0], acc[m][nf], 0, 0, 0);
            #pragma unroll
            for (int m = 0; m < 4; ++m)
                acc[m][nf] = __builtin_amdgcn_mfma_f32_16x16x32_bf16(b1, af[m][1], acc[m][nf], 0, 0, 0);
        }
        __builtin_amdgcn_s_setprio(0);
        // boundary: land loads, write A(t+1), issue x(t+2), one barrier
        if (t + 1 < NT_K) {
            __builtin_amdgcn_sched_barrier(0);
            asm volatile("s_waitcnt vmcnt(0)" ::: "memory");
            __builtin_amdgcn_sched_barrier(0);
            writeA(paN);
            if (t + 2 < NT_K) loadA(t + 2);            // 4 VMEM, in flight across next tile
            asm volatile("s_waitcnt lgkmcnt(0)" ::: "memory");
            __builtin_amdgcn_sched_barrier(0);
            __builtin_amdgcn_s_barrier();
            char* ta = paC; paC = paN; paN = ta;
            char* tb = pbC; pbC = pbN; pbN = tb;
        }
    }

    // epilogue: D col(lane&15)=M-row, D row-regs = 4 consecutive N-cols (operands swapped)
    const int rowb = (bx << 8) + wm * 64 + (lane & 15);
    const int colb = blockN + wn * 96 + ((lane >> 4) << 2);
    const float g = gamma[0];
    if (g == 0.f) {
        #pragma unroll
        for (int mf = 0; mf < 4; ++mf) {
            const int row = rowb + mf * 16;
            const int px = row % NP;
            #pragma unroll
            for (int nf = 0; nf < 6; ++nf) {
                const int col = colb + nf * 16;
                float4 bs4 = *(const float4*)(bias + col);
                float4 pv  = *(const float4*)(pos + (size_t)px * HID + col);
                f32x4 a = acc[mf][nf];
                float4 o;
                o.x = a[0] + bs4.x + pv.x;
                o.y = a[1] + bs4.y + pv.y;
                o.z = a[2] + bs4.z + pv.z;
                o.w = a[3] + bs4.w + pv.w;
                *reinterpret_cast<float4*>(outF + (size_t)row * HID + col) = o;
            }
        }
    } else {
        #pragma unroll
        for (int mf = 0; mf < 4; ++mf) {
            const int row = rowb + mf * 16;
            #pragma unroll
            for (int nf = 0; nf < 6; ++nf) {
                const int col = colb + nf * 16;
                float4 bs4 = *(const float4*)(bias + col);
                f32x4 a = acc[mf][nf];
                ushort4 o;
                o.x = f2bf(a[0] + bs4.x);
                o.y = f2bf(a[1] + bs4.y);
                o.z = f2bf(a[2] + bs4.z);
                o.w = f2bf(a[3] + bs4.w);
                *reinterpret_cast<ushort4*>(Y + kp_addr(row, col)) = o;
            }
        }
    }
}

// ============ GEMM2 (gamma!=0 only): VQK = Y @ Wvqk^T + Bvqk ============
__device__ __forceinline__ void stageA_half(const unsigned short* __restrict__ Ap,
        size_t tilebase, int h, char* ldsregion, int rl, int sp, int ldsoff0) {
    const unsigned short* g0 = Ap + tilebase + (size_t)(h * 128 + rl) * 64 + sp * 8;
    gload_lds16(g0, ldsregion + ldsoff0);
    gload_lds16(g0 + 512, ldsregion + ldsoff0 + 1024);
}

__global__ __launch_bounds__(512, 2) void k_gemm256(
    const unsigned short* __restrict__ A, const unsigned short* __restrict__ Bw,
    const float* __restrict__ bias, unsigned short* __restrict__ C,
    const float* __restrict__ gamma, int NT)
{
    if (gamma[0] == 0.f) return;
    extern __shared__ char smem[];
    const int tid  = threadIdx.x;
    const int lane = tid & 63;
    const int w    = tid >> 6;
    const int wm   = w >> 2;
    const int wn   = w & 3;
    const int nwg = gridDim.x;
    const int chunk = nwg >> 3;
    const int bid = blockIdx.x;
    const int bs = (bid & 7) * chunk + (bid >> 3);
    const int bx = bs / NT, by = bs - (bs / NT) * NT;
    const int blockN = by << 8;
    const int rl = (w << 4) + (lane >> 3);
    const int sp = (lane & 7) ^ (lane >> 3);
    const int ldsoff0 = (w << 11) + (lane << 4);
    const int lx   = (lane & 15) << 7;
    const int swz  = (lane & 7) << 4;
    const int cbx0 = (((lane >> 4) << 4)) ^ swz;
    const int cbx1 = (64 + ((lane >> 4) << 4)) ^ swz;
    char* pa0 = smem;
    char* pa1 = smem + 32768;
    char* pa2 = smem + 65536;
    char* pb0 = smem + 98304;
    char* pb1 = smem + 131072;
    const size_t atile0 = ((size_t)bx * NT_K) << 14;

    stageB_half(Bw, blockN,       pb0,         0,  rl, sp, ldsoff0);
    stageB_half(Bw, blockN + 128, pb0 + 16384, 0,  rl, sp, ldsoff0);
    stageA_half(A, atile0,         0, pa0,         rl, sp, ldsoff0);
    stageA_half(A, atile0,         1, pa0 + 16384, rl, sp, ldsoff0);
    stageA_half(A, atile0 + 16384, 0, pa1,         rl, sp, ldsoff0);
    stageA_half(A, atile0 + 16384, 1, pa1 + 16384, rl, sp, ldsoff0);

    f32x4 acc[8][4] = {};
    asm volatile("s_waitcnt vmcnt(4)" ::: "memory");
    __builtin_amdgcn_sched_barrier(0);
    __builtin_amdgcn_s_barrier();

    for (int t = 0; t < NT_K; ++t) {
        if (t + 1 < NT_K) {
            stageB_half(Bw, blockN,       pb1,         (t + 1) << 6, rl, sp, ldsoff0);
            stageB_half(Bw, blockN + 128, pb1 + 16384, (t + 1) << 6, rl, sp, ldsoff0);
        }
        if (t + 2 < NT_K) {
            const size_t tb = atile0 + ((size_t)(t + 2) << 14);
            stageA_half(A, tb, 0, pa2,         rl, sp, ldsoff0);
            stageA_half(A, tb, 1, pa2 + 16384, rl, sp, ldsoff0);
        }
        s16x8 bfr[4][2];
        #pragma unroll
        for (int nf = 0; nf < 4; ++nf) {
            const int rb = wn * 8192 + nf * 2048 + lx;
            bfr[nf][0] = *(const s16x8*)(pb0 + rb + cbx0);
            bfr[nf][1] = *(const s16x8*)(pb0 + rb + cbx1);
        }
        #pragma unroll
        for (int half = 0; half < 2; ++half) {
            s16x8 af[4][2];
            #pragma unroll
            for (int m = 0; m < 4; ++m) {
                const int rb0 = wm * 16384 + (half * 4 + m) * 2048 + lx;
                af[m][0] = *(const s16x8*)(pa0 + rb0 + cbx0);
                af[m][1] = *(const s16x8*)(pa0 + rb0 + cbx1);
            }
            __builtin_amdgcn_s_setprio(1);
            #pragma unroll
            for (int kh = 0; kh < 2; ++kh)
                #pragma unroll
                for (int m = 0; m < 4; ++m)
                    #pragma unroll
                    for (int nf = 0; nf < 4; ++nf)
                        acc[half * 4 + m][nf] = __builtin_amdgcn_mfma_f32_16x16x32_bf16(
                            bfr[nf][kh], af[m][kh], acc[half * 4 + m][nf], 0, 0, 0);
            __builtin_amdgcn_s_setprio(0);
        }
        if (t < NT_K - 1) {
            __builtin_amdgcn_sched_barrier(0);
            if (t >= NT_K - 3) { asm volatile("s_waitcnt vmcnt(0)" ::: "memory"); }
            else               { asm volatile("s_waitcnt vmcnt(4)" ::: "memory"); }
            __builtin_amdgcn_s_barrier();
            __builtin_amdgcn_sched_barrier(0);
        }
        char* ta = pa0; pa0 = pa1; pa1 = pa2; pa2 = ta;
        char* tb = pb0; pb0 = pb1; pb1 = tb;
    }

    const int rowb = (bx << 8) + wm * 128 + (lane & 15);
    const int colb = blockN + wn * 64 + ((lane >> 4) << 2);
    #pragma unroll
    for (int mf = 0; mf < 8; ++mf) {
        const int row = rowb + mf * 16;
        #pragma unroll
        for (int nf = 0; nf < 4; ++nf) {
            const int col = colb + nf * 16;
            float4 bs4 = *(const float4*)(bias + col);
            f32x4 a = acc[mf][nf];
            ushort4 o;
            o.x = f2bf(a[0] + bs4.x);
            o.y = f2bf(a[1] + bs4.y);
            o.z = f2bf(a[2] + bs4.z);
            o.w = f2bf(a[3] + bs4.w);
            *reinterpret_cast<ushort4*>(C + (size_t)row * (NT << 8) + col) = o;
        }
    }
}

// ---------------- energies H (gamma!=0) ----------------
__global__ __launch_bounds__(256) void k_energyH(const unsigned short* __restrict__ VQK,
                                                 float* __restrict__ E, const float* __restrict__ gam) {
    if (gam[0] == 0.f) return;
    __shared__ float qs[24][97], ks[24][97];
    const int b = blockIdx.x / HW24, w = blockIdx.x % HW24;
    const int tid = threadIdx.x;
    for (int idx = tid; idx < 24 * 12; idx += 256) {
        int i = idx / 12, c = (idx % 12) * 8;
        size_t base = ((size_t)(b * NP + i * HW24 + w)) * NVQK + 768;
        s16x8 qv = *(const s16x8*)(VQK + base + c);
        s16x8 kv = *(const s16x8*)(VQK + base + 96 + c);
        #pragma unroll
        for (int u = 0; u < 8; u++) {
            qs[i][c + u] = bf2f((unsigned short)qv[u]);
            ks[i][c + u] = bf2f((unsigned short)kv[u]);
        }
    }
    __syncthreads();
    for (int idx = tid; idx < 576; idx += 256) {
        int i = idx / 24, j = idx - (idx / 24) * 24;
        float s = NEGINF;
        if (i != j) {
            s = 0.f;
            #pragma unroll 8
            for (int c = 0; c < 96; c++) s += qs[i][c] * ks[j][c];
        }
        E[((size_t)(b * NP + i * HW24 + w)) * 48 + j] = s;
    }
}

// ---------------- energies W + softmax (gamma!=0) ----------------
__global__ __launch_bounds__(256) void k_energyW(const unsigned short* __restrict__ VQK,
                                                 float* __restrict__ E, const float* __restrict__ gam) {
    if (gam[0] == 0.f) return;
    __shared__ float qs[24][97], ks[24][97], ew[24][24];
    const int b = blockIdx.x / HW24, h = blockIdx.x % HW24;
    const int tid = threadIdx.x;
    const int prow = b * NP + h * HW24;
    for (int idx = tid; idx < 24 * 12; idx += 256) {
        int i = idx / 12, c = (idx % 12) * 8;
        size_t base = ((size_t)(prow + i)) * NVQK + 768;
        s16x8 qv = *(const s16x8*)(VQK + base + c);
        s16x8 kv = *(const s16x8*)(VQK + base + 96 + c);
        #pragma unroll
        for (int u = 0; u < 8; u++) {
            qs[i][c + u] = bf2f((unsigned short)qv[u]);
            ks[i][c + u] = bf2f((unsigned short)kv[u]);
        }
    }
    __syncthreads();
    for (int idx = tid; idx < 576; idx += 256) {
        int i = idx / 24, j = idx - (idx / 24) * 24;
        float s = 0.f;
        #pragma unroll 8
        for (int c = 0; c < 96; c++) s += qs[i][c] * ks[j][c];
        ew[i][j] = s;
    }
    __syncthreads();
    if (tid < 24) {
        size_t p = prow + tid;
        float e[48];
        #pragma unroll
        for (int j = 0; j < 24; j++) e[j] = E[p * 48 + j];
        #pragma unroll
        for (int j = 0; j < 24; j++) e[24 + j] = ew[tid][j];
        float mx = NEGINF;
        #pragma unroll
        for (int j = 0; j < 48; j++) mx = fmaxf(mx, e[j]);
        float sum = 0.f;
        #pragma unroll
        for (int j = 0; j < 48; j++) { e[j] = __expf(e[j] - mx); sum += e[j]; }
        float inv = 1.f / sum;
        #pragma unroll
        for (int j = 0; j < 48; j++) E[p * 48 + j] = e[j] * inv;
    }
}

// ---------------- pass H (gamma!=0) ----------------
__global__ __launch_bounds__(192) void k_passH(const float* __restrict__ E,
        const unsigned short* __restrict__ VQK, const unsigned short* __restrict__ Y,
        const float* __restrict__ gamma, const float* __restrict__ pos,
        float* __restrict__ out) {
    const float g = gamma[0];
    if (g == 0.f) return;
    __shared__ float att[576];
    int bid = (blockIdx.x & 7) * 192 + (blockIdx.x >> 3);
    const int b = bid / HW24, w = bid % HW24;
    const int tid = threadIdx.x;
    for (int idx = tid; idx < 576; idx += 192) {
        int i = idx / 24, j = idx - (idx / 24) * 24;
        att[idx] = E[((size_t)(b * NP + i * HW24 + w)) * 48 + j];
    }
    __syncthreads();
    float vf[24][4];
    #pragma unroll
    for (int j = 0; j < 24; j++) {
        ushort4 vv = *(const ushort4*)(VQK + ((size_t)(b * NP + j * HW24 + w)) * NVQK + 4 * tid);
        vf[j][0] = bf2f(vv.x); vf[j][1] = bf2f(vv.y); vf[j][2] = bf2f(vv.z); vf[j][3] = bf2f(vv.w);
    }
    #pragma unroll
    for (int i = 0; i < 24; i++) {
        float a0 = 0.f, a1 = 0.f, a2 = 0.f, a3 = 0.f;
        #pragma unroll
        for (int j = 0; j < 24; j++) {
            float a = att[i * 24 + j];
            a0 += a * vf[j][0]; a1 += a * vf[j][1]; a2 += a * vf[j][2]; a3 += a * vf[j][3];
        }
        size_t p = (size_t)(b * NP + i * HW24 + w);
        ushort4 yv = *(const ushort4*)(Y + kp_addr((int)p, 4 * tid));
        float4 pv = *(const float4*)(pos + (size_t)(i * HW24 + w) * HID + 4 * tid);
        float4 o;
        o.x = g * a0 + bf2f(yv.x) + pv.x;
        o.y = g * a1 + bf2f(yv.y) + pv.y;
        o.z = g * a2 + bf2f(yv.z) + pv.z;
        o.w = g * a3 + bf2f(yv.w) + pv.w;
        *reinterpret_cast<float4*>(out + p * HID + 4 * tid) = o;
    }
}

// ---------------- pass W (gamma!=0) ----------------
__global__ __launch_bounds__(192) void k_passW(const float* __restrict__ E,
        const unsigned short* __restrict__ VQK, const float* __restrict__ gamma,
        float* __restrict__ out) {
    const float g = gamma[0];
    if (g == 0.f) return;
    __shared__ float att[576];
    int bid = (blockIdx.x & 7) * 192 + (blockIdx.x >> 3);
    const int b = bid / HW24, h = bid % HW24;
    const int tid = threadIdx.x;
    const int prow = b * NP + h * HW24;
    for (int idx = tid; idx < 576; idx += 192) {
        int i = idx / 24, j = idx - (idx / 24) * 24;
        att[idx] = E[((size_t)(prow + i)) * 48 + 24 + j];
    }
    __syncthreads();
    float vf[24][4];
    #pragma unroll
    for (int j = 0; j < 24; j++) {
        ushort4 vv = *(const ushort4*)(VQK + ((size_t)(prow + j)) * NVQK + 4 * tid);
        vf[j][0] = bf2f(vv.x); vf[j][1] = bf2f(vv.y); vf[j][2] = bf2f(vv.z); vf[j][3] = bf2f(vv.w);
    }
    #pragma unroll
    for (int i = 0; i < 24; i++) {
        float a0 = 0.f, a1 = 0.f, a2 = 0.f, a3 = 0.f;
        #pragma unroll
        for (int j = 0; j < 24; j++) {
            float a = att[i * 24 + j];
            a0 += a * vf[j][0]; a1 += a * vf[j][1]; a2 += a * vf[j][2]; a3 += a * vf[j][3];
        }
        size_t p = (size_t)(prow + i);
        float4 o = *reinterpret_cast<const float4*>(out + p * HID + 4 * tid);
        o.x += g * a0; o.y += g * a1; o.z += g * a2; o.w += g * a3;
        *reinterpret_cast<float4*>(out + p * HID + 4 * tid) = o;
    }
}

extern "C" void kernel_launch(void* const* d_in, const int* in_sizes, int n_in,
                              void* d_out, int out_size, void* d_ws, size_t ws_size,
                              hipStream_t stream) {
    const float* x       = (const float*)d_in[0];
    const float* patch_w = (const float*)d_in[1];
    const float* patch_b = (const float*)d_in[2];
    const float* wq      = (const float*)d_in[3];
    const float* bq      = (const float*)d_in[4];
    const float* wk      = (const float*)d_in[5];
    const float* bk      = (const float*)d_in[6];
    const float* wv      = (const float*)d_in[7];
    const float* bv      = (const float*)d_in[8];
    const float* gamma   = (const float*)d_in[9];
    const float* pos_emb = (const float*)d_in[10];
    float* out = (float*)d_out;

    hipFuncSetAttribute(reinterpret_cast<const void*>(k_gemmFused),
                        hipFuncAttributeMaxDynamicSharedMemorySize, 163840);
    hipFuncSetAttribute(reinterpret_cast<const void*>(k_gemm256),
                        hipFuncAttributeMaxDynamicSharedMemorySize, 163840);

    char* ws = (char*)d_ws;
    size_t off = 0;
    auto alloc = [&](size_t bytes) { char* pp = ws + off; off += (bytes + 255) & ~(size_t)255; return pp; };
    unsigned short* VQK = (unsigned short*)alloc((size_t)MROWS * NVQK * 2);
    unsigned short* Y   = (unsigned short*)alloc((size_t)MROWS * HID * 2);  // K-packed (gamma!=0 path)
    unsigned short* Wp  = (unsigned short*)alloc((size_t)HID * HID * 2);
    unsigned short* Wvqk= (unsigned short*)alloc((size_t)NVQK * HID * 2);
    float*          Bvqk= (float*)alloc(NVQK * 4);
    float*          E   = (float*)alloc((size_t)MROWS * 48 * 4);

    k_prep<<<dim3((NVQK * HID + 255) / 256), dim3(256), 0, stream>>>(patch_w, wq, wk, wv, bq, bk, bv, Wp, Wvqk, Bvqk);
    // fused im2col + patch GEMM (256x384 tiles, grid 144*2 = 288); gamma==0 -> out = y + pos (f32)
    k_gemmFused<<<dim3((MROWS / 256) * 2), dim3(1024), 163840, stream>>>(
        x, Wp, patch_b, Y, out, pos_emb, gamma);
    // ---- gamma!=0 full path (all guarded; no-ops for gamma==0) ----
    k_gemm256<<<dim3((MROWS / 256) * (NVQK / 256)), dim3(512), 163840, stream>>>(
        Y, Wvqk, Bvqk, VQK, gamma, NVQK / 256);
    k_energyH<<<dim3(BATCH * HW24), dim3(256), 0, stream>>>(VQK, E, gamma);
    k_energyW<<<dim3(BATCH * HW24), dim3(256), 0, stream>>>(VQK, E, gamma);
    k_passH<<<dim3(BATCH * HW24), dim3(192), 0, stream>>>(E, VQK, Y, gamma, pos_emb, out);
    k_passW<<<dim3(BATCH * HW24), dim3(192), 0, stream>>>(E, VQK, gamma, out);
}

// Round 13
// 111.881 us; speedup vs baseline: 3.8150x; 3.8150x over previous
//
#include <hip/hip_runtime.h>
#include <hip/hip_bf16.h>
#include <cstdint>

#define BATCH 64
#define CIN 3
#define IMG 384
#define PATCH 16
#define HID 768
#define CQ 96
#define HW24 24
#define NP 576
#define MROWS (BATCH*NP)   /* 36864 */
#define KDIM 768
#define NVQK 1024          /* V(768) + Q(96) + K(96) + pad(64) */
#define NT_K 12            /* 768 / 64 K-tiles */
#define NEGINF (-1e30f)

typedef __attribute__((ext_vector_type(8))) short s16x8;
typedef __attribute__((ext_vector_type(4))) float f32x4;

__device__ __forceinline__ float bf2f(unsigned short u) {
    union { unsigned int i; float f; } x; x.i = ((unsigned int)u) << 16; return x.f;
}
__device__ __forceinline__ unsigned short f2bf(float f) {
    union { float f; unsigned int i; } x; x.f = f;
    unsigned int r = x.i + 0x7fffu + ((x.i >> 16) & 1u);
    return (unsigned short)(r >> 16);
}
__device__ __forceinline__ unsigned int f2bf2(float a, float b) {
    union { __hip_bfloat162 h; unsigned int u; } c;
    c.h = __float22bfloat162_rn(make_float2(a, b));
    return c.u;
}

__device__ __forceinline__ void gload_lds16(const void* g, void* l) {
    __builtin_amdgcn_global_load_lds(
        (const __attribute__((address_space(1))) void*)(uintptr_t)g,
        (__attribute__((address_space(3))) void*)(uint32_t)(uintptr_t)l,
        16, 0, 0);
}

// K-packed matrix layout: [mt][kt][256][64]
__device__ __forceinline__ size_t kp_addr(int row, int col) {
    return (((size_t)(row >> 8) * NT_K + (col >> 6)) * 256 + (row & 255)) * 64 + (col & 63);
}

// ---------------- weight prep ----------------
__global__ void k_prep(const float* __restrict__ pw, const float* __restrict__ wq,
                       const float* __restrict__ wk, const float* __restrict__ wv,
                       const float* __restrict__ bq, const float* __restrict__ bk,
                       const float* __restrict__ bv,
                       unsigned short* __restrict__ Wp, unsigned short* __restrict__ Wvqk,
                       float* __restrict__ Bvqk) {
    int t = blockIdx.x * 256 + threadIdx.x;
    if (t < HID * HID) Wp[t] = f2bf(pw[t]);
    if (t < NVQK * HID) {
        int row = t / HID; int col = t - row * HID;
        float val = 0.f;
        if (row < 768) val = wv[t];
        else if (row < 864) val = wq[(row - 768) * HID + col];
        else if (row < 960) val = wk[(row - 864) * HID + col];
        Wvqk[t] = f2bf(val);
    }
    if (t < NVQK) {
        float v = 0.f;
        if (t < 768) v = bv[t]; else if (t < 864) v = bq[t - 768]; else if (t < 960) v = bk[t - 864];
        Bvqk[t] = v;
    }
}

// ============ FUSED im2col + 256x256x64 bf16 GEMM (patch-embed) — proven 112us config ============
// Reads x (f32 NCHW) directly; A-tile reg-staged (8 float4 loads/thread, packed cvt,
// 4 swizzled ds_write_b128). B via gload_lds linear-dest + pre-swizzled source.
// LDS 128KB: A dbuf 2x32KB @ 0/32K, B dbuf 2x32KB @ 64K/96K. One barrier + one vmcnt(0)/tile.
// gamma==0: epilogue writes f32 out = acc+bias+pos (final). gamma!=0: writes Y (K-packed bf16).
__device__ __forceinline__ void stageB_half(const unsigned short* __restrict__ gmat,
        int growbase, char* ldsregion, int kcol, int rl, int sp, int ldsoff0) {
    const unsigned short* g0 = gmat + (size_t)(growbase + rl) * KDIM + kcol + sp * 8;
    gload_lds16(g0, ldsregion + ldsoff0);
    gload_lds16(g0 + (size_t)8 * KDIM, ldsregion + ldsoff0 + 1024);
}

__global__ __launch_bounds__(512, 2) void k_gemmFused(
    const float* __restrict__ x, const unsigned short* __restrict__ Bw,
    const float* __restrict__ bias, unsigned short* __restrict__ Y,
    float* __restrict__ outF, const float* __restrict__ pos,
    const float* __restrict__ gamma)
{
    extern __shared__ char smem[];
    const int tid  = threadIdx.x;
    const int lane = tid & 63;
    const int w    = tid >> 6;
    const int wm   = w >> 2;
    const int wn   = w & 3;

    // XCD chunk swizzle (432 % 8 == 0), A-tile-major (bs/3): N-siblings adjacent -> share x via L2
    const int nwg = gridDim.x;
    const int chunk = nwg >> 3;
    const int bid = blockIdx.x;
    const int bs = (bid & 7) * chunk + (bid >> 3);
    const int bx = bs / 3, by = bs - (bs / 3) * 3;
    const int blockN = by << 8;

    // B staging constants (linear dest, pre-swizzled source)
    const int rl = (w << 4) + (lane >> 3);
    const int sp = (lane & 7) ^ (lane >> 3);
    const int ldsoff0 = (w << 11) + (lane << 4);

    // ds_read constants (byte ^= (row&7)<<4 within 128B row)
    const int lx   = (lane & 15) << 7;
    const int swz  = (lane & 7) << 4;
    const int cbx0 = (((lane >> 4) << 4)) ^ swz;
    const int cbx1 = (64 + ((lane >> 4) << 4)) ^ swz;

    // A staging constants: thread -> row rr (0..255), 32-col half ch
    const int rr  = tid >> 1;
    const int ch  = (tid & 1) << 5;        // local col base 0/32
    const int iib = ch >> 4;               // i sub-offset 0/2
    const int grow = (bx << 8) + rr;
    const int b  = grow / NP;
    const int p  = grow - b * NP;
    const int ph = p / HW24, pw = p - ph * HW24;
    const float* xrow = x + (size_t)b * (CIN * IMG * IMG) + ph * (PATCH * IMG) + pw * PATCH;
    const int swzr  = (rr & 7) << 4;
    const int wbase = rr * 128;

    char* Acur = smem;
    char* Anxt = smem + 32768;
    char* Bcur = smem + 65536;
    char* Bnxt = smem + 98304;

    float4 ld[8];
    // loadA: issue 8 float4 loads of tile t's 32 source floats x2 (two i rows x 16 j)
    auto loadA = [&](int t) {
        const float* src = xrow + (t >> 2) * (IMG * IMG) + ((t & 3) * 4 + iib) * IMG;
        #pragma unroll
        for (int u = 0; u < 4; ++u) {
            const float* s2 = src + (u >> 1) * IMG + ((u & 1) << 3);
            ld[2 * u]     = *(const float4*)s2;
            ld[2 * u + 1] = *(const float4*)(s2 + 4);
        }
    };
    auto writeA = [&](char* dst) {
        #pragma unroll
        for (int u = 0; u < 4; ++u) {
            int4 pk;
            pk.x = f2bf2(ld[2 * u].x,     ld[2 * u].y);
            pk.y = f2bf2(ld[2 * u].z,     ld[2 * u].w);
            pk.z = f2bf2(ld[2 * u + 1].x, ld[2 * u + 1].y);
            pk.w = f2bf2(ld[2 * u + 1].z, ld[2 * u + 1].w);
            *reinterpret_cast<int4*>(dst + wbase + ((ch * 2 + u * 16) ^ swzr)) = pk;
        }
    };

    // prologue: A(0) regs + B(0) lds
    loadA(0);
    stageB_half(Bw, blockN,       Bcur,         0, rl, sp, ldsoff0);
    stageB_half(Bw, blockN + 128, Bcur + 16384, 0, rl, sp, ldsoff0);
    asm volatile("s_waitcnt vmcnt(0)" ::: "memory");
    __builtin_amdgcn_sched_barrier(0);
    writeA(Acur);
    asm volatile("s_waitcnt lgkmcnt(0)" ::: "memory");
    __builtin_amdgcn_sched_barrier(0);
    __builtin_amdgcn_s_barrier();

    f32x4 acc[8][4] = {};

    for (int t = 0; t < NT_K; ++t) {
        // issue next-tile loads early (overlap with this tile's compute)
        if (t + 1 < NT_K) {
            loadA(t + 1);
            stageB_half(Bw, blockN,       Bnxt,         (t + 1) << 6, rl, sp, ldsoff0);
            stageB_half(Bw, blockN + 128, Bnxt + 16384, (t + 1) << 6, rl, sp, ldsoff0);
        }
        // B fragments
        s16x8 bfr[4][2];
        #pragma unroll
        for (int nf = 0; nf < 4; ++nf) {
            const int rb = wn * 8192 + nf * 2048 + lx;
            bfr[nf][0] = *(const s16x8*)(Bcur + rb + cbx0);
            bfr[nf][1] = *(const s16x8*)(Bcur + rb + cbx1);
        }
        #pragma unroll
        for (int half = 0; half < 2; ++half) {
            s16x8 af[4][2];
            #pragma unroll
            for (int m = 0; m < 4; ++m) {
                const int rb0 = wm * 16384 + (half * 4 + m) * 2048 + lx;
                af[m][0] = *(const s16x8*)(Acur + rb0 + cbx0);
                af[m][1] = *(const s16x8*)(Acur + rb0 + cbx1);
            }
            __builtin_amdgcn_s_setprio(1);
            #pragma unroll
            for (int kh = 0; kh < 2; ++kh)
                #pragma unroll
                for (int m = 0; m < 4; ++m)
                    #pragma unroll
                    for (int nf = 0; nf < 4; ++nf)
                        acc[half * 4 + m][nf] = __builtin_amdgcn_mfma_f32_16x16x32_bf16(
                            bfr[nf][kh], af[m][kh], acc[half * 4 + m][nf], 0, 0, 0);
            __builtin_amdgcn_s_setprio(0);
        }
        // tile boundary: land loads, write A(t+1), one barrier
        if (t + 1 < NT_K) {
            __builtin_amdgcn_sched_barrier(0);
            asm volatile("s_waitcnt vmcnt(0)" ::: "memory");
            __builtin_amdgcn_sched_barrier(0);
            writeA(Anxt);
            asm volatile("s_waitcnt lgkmcnt(0)" ::: "memory");
            __builtin_amdgcn_sched_barrier(0);
            __builtin_amdgcn_s_barrier();
            char* ta = Acur; Acur = Anxt; Anxt = ta;
            char* tb = Bcur; Bcur = Bnxt; Bnxt = tb;
        }
    }

    // epilogue: D col(lane&15)=M-row, D row-regs = 4 consecutive N-cols (operands swapped)
    const int rowb = (bx << 8) + wm * 128 + (lane & 15);
    const int colb = blockN + wn * 64 + ((lane >> 4) << 2);
    const float g = gamma[0];
    if (g == 0.f) {
        #pragma unroll
        for (int mf = 0; mf < 8; ++mf) {
            const int row = rowb + mf * 16;
            const int px = row % NP;
            #pragma unroll
            for (int nf = 0; nf < 4; ++nf) {
                const int col = colb + nf * 16;
                float4 bs4 = *(const float4*)(bias + col);
                float4 pv  = *(const float4*)(pos + (size_t)px * HID + col);
                f32x4 a = acc[mf][nf];
                float4 o;
                o.x = a[0] + bs4.x + pv.x;
                o.y = a[1] + bs4.y + pv.y;
                o.z = a[2] + bs4.z + pv.z;
                o.w = a[3] + bs4.w + pv.w;
                *reinterpret_cast<float4*>(outF + (size_t)row * HID + col) = o;
            }
        }
    } else {
        #pragma unroll
        for (int mf = 0; mf < 8; ++mf) {
            const int row = rowb + mf * 16;
            #pragma unroll
            for (int nf = 0; nf < 4; ++nf) {
                const int col = colb + nf * 16;
                float4 bs4 = *(const float4*)(bias + col);
                f32x4 a = acc[mf][nf];
                ushort4 o;
                o.x = f2bf(a[0] + bs4.x);
                o.y = f2bf(a[1] + bs4.y);
                o.z = f2bf(a[2] + bs4.z);
                o.w = f2bf(a[3] + bs4.w);
                *reinterpret_cast<ushort4*>(Y + kp_addr(row, col)) = o;
            }
        }
    }
}

// ============ GEMM2 (gamma!=0 only): VQK = Y @ Wvqk^T + Bvqk ============
__device__ __forceinline__ void stageA_half(const unsigned short* __restrict__ Ap,
        size_t tilebase, int h, char* ldsregion, int rl, int sp, int ldsoff0) {
    const unsigned short* g0 = Ap + tilebase + (size_t)(h * 128 + rl) * 64 + sp * 8;
    gload_lds16(g0, ldsregion + ldsoff0);
    gload_lds16(g0 + 512, ldsregion + ldsoff0 + 1024);
}

__global__ __launch_bounds__(512, 2) void k_gemm256(
    const unsigned short* __restrict__ A, const unsigned short* __restrict__ Bw,
    const float* __restrict__ bias, unsigned short* __restrict__ C,
    const float* __restrict__ gamma, int NT)
{
    if (gamma[0] == 0.f) return;
    extern __shared__ char smem[];
    const int tid  = threadIdx.x;
    const int lane = tid & 63;
    const int w    = tid >> 6;
    const int wm   = w >> 2;
    const int wn   = w & 3;
    const int nwg = gridDim.x;
    const int chunk = nwg >> 3;
    const int bid = blockIdx.x;
    const int bs = (bid & 7) * chunk + (bid >> 3);
    const int bx = bs / NT, by = bs - (bs / NT) * NT;
    const int blockN = by << 8;
    const int rl = (w << 4) + (lane >> 3);
    const int sp = (lane & 7) ^ (lane >> 3);
    const int ldsoff0 = (w << 11) + (lane << 4);
    const int lx   = (lane & 15) << 7;
    const int swz  = (lane & 7) << 4;
    const int cbx0 = (((lane >> 4) << 4)) ^ swz;
    const int cbx1 = (64 + ((lane >> 4) << 4)) ^ swz;
    char* pa0 = smem;
    char* pa1 = smem + 32768;
    char* pa2 = smem + 65536;
    char* pb0 = smem + 98304;
    char* pb1 = smem + 131072;
    const size_t atile0 = ((size_t)bx * NT_K) << 14;

    stageB_half(Bw, blockN,       pb0,         0,  rl, sp, ldsoff0);
    stageB_half(Bw, blockN + 128, pb0 + 16384, 0,  rl, sp, ldsoff0);
    stageA_half(A, atile0,         0, pa0,         rl, sp, ldsoff0);
    stageA_half(A, atile0,         1, pa0 + 16384, rl, sp, ldsoff0);
    stageA_half(A, atile0 + 16384, 0, pa1,         rl, sp, ldsoff0);
    stageA_half(A, atile0 + 16384, 1, pa1 + 16384, rl, sp, ldsoff0);

    f32x4 acc[8][4] = {};
    asm volatile("s_waitcnt vmcnt(4)" ::: "memory");
    __builtin_amdgcn_sched_barrier(0);
    __builtin_amdgcn_s_barrier();

    for (int t = 0; t < NT_K; ++t) {
        if (t + 1 < NT_K) {
            stageB_half(Bw, blockN,       pb1,         (t + 1) << 6, rl, sp, ldsoff0);
            stageB_half(Bw, blockN + 128, pb1 + 16384, (t + 1) << 6, rl, sp, ldsoff0);
        }
        if (t + 2 < NT_K) {
            const size_t tb = atile0 + ((size_t)(t + 2) << 14);
            stageA_half(A, tb, 0, pa2,         rl, sp, ldsoff0);
            stageA_half(A, tb, 1, pa2 + 16384, rl, sp, ldsoff0);
        }
        s16x8 bfr[4][2];
        #pragma unroll
        for (int nf = 0; nf < 4; ++nf) {
            const int rb = wn * 8192 + nf * 2048 + lx;
            bfr[nf][0] = *(const s16x8*)(pb0 + rb + cbx0);
            bfr[nf][1] = *(const s16x8*)(pb0 + rb + cbx1);
        }
        #pragma unroll
        for (int half = 0; half < 2; ++half) {
            s16x8 af[4][2];
            #pragma unroll
            for (int m = 0; m < 4; ++m) {
                const int rb0 = wm * 16384 + (half * 4 + m) * 2048 + lx;
                af[m][0] = *(const s16x8*)(pa0 + rb0 + cbx0);
                af[m][1] = *(const s16x8*)(pa0 + rb0 + cbx1);
            }
            __builtin_amdgcn_s_setprio(1);
            #pragma unroll
            for (int kh = 0; kh < 2; ++kh)
                #pragma unroll
                for (int m = 0; m < 4; ++m)
                    #pragma unroll
                    for (int nf = 0; nf < 4; ++nf)
                        acc[half * 4 + m][nf] = __builtin_amdgcn_mfma_f32_16x16x32_bf16(
                            bfr[nf][kh], af[m][kh], acc[half * 4 + m][nf], 0, 0, 0);
            __builtin_amdgcn_s_setprio(0);
        }
        if (t < NT_K - 1) {
            __builtin_amdgcn_sched_barrier(0);
            if (t >= NT_K - 3) { asm volatile("s_waitcnt vmcnt(0)" ::: "memory"); }
            else               { asm volatile("s_waitcnt vmcnt(4)" ::: "memory"); }
            __builtin_amdgcn_s_barrier();
            __builtin_amdgcn_sched_barrier(0);
        }
        char* ta = pa0; pa0 = pa1; pa1 = pa2; pa2 = ta;
        char* tb = pb0; pb0 = pb1; pb1 = tb;
    }

    const int rowb = (bx << 8) + wm * 128 + (lane & 15);
    const int colb = blockN + wn * 64 + ((lane >> 4) << 2);
    #pragma unroll
    for (int mf = 0; mf < 8; ++mf) {
        const int row = rowb + mf * 16;
        #pragma unroll
        for (int nf = 0; nf < 4; ++nf) {
            const int col = colb + nf * 16;
            float4 bs4 = *(const float4*)(bias + col);
            f32x4 a = acc[mf][nf];
            ushort4 o;
            o.x = f2bf(a[0] + bs4.x);
            o.y = f2bf(a[1] + bs4.y);
            o.z = f2bf(a[2] + bs4.z);
            o.w = f2bf(a[3] + bs4.w);
            *reinterpret_cast<ushort4*>(C + (size_t)row * (NT << 8) + col) = o;
        }
    }
}

// ---------------- energies H (gamma!=0) ----------------
__global__ __launch_bounds__(256) void k_energyH(const unsigned short* __restrict__ VQK,
                                                 float* __restrict__ E, const float* __restrict__ gam) {
    if (gam[0] == 0.f) return;
    __shared__ float qs[24][97], ks[24][97];
    const int b = blockIdx.x / HW24, w = blockIdx.x % HW24;
    const int tid = threadIdx.x;
    for (int idx = tid; idx < 24 * 12; idx += 256) {
        int i = idx / 12, c = (idx % 12) * 8;
        size_t base = ((size_t)(b * NP + i * HW24 + w)) * NVQK + 768;
        s16x8 qv = *(const s16x8*)(VQK + base + c);
        s16x8 kv = *(const s16x8*)(VQK + base + 96 + c);
        #pragma unroll
        for (int u = 0; u < 8; u++) {
            qs[i][c + u] = bf2f((unsigned short)qv[u]);
            ks[i][c + u] = bf2f((unsigned short)kv[u]);
        }
    }
    __syncthreads();
    for (int idx = tid; idx < 576; idx += 256) {
        int i = idx / 24, j = idx - (idx / 24) * 24;
        float s = NEGINF;
        if (i != j) {
            s = 0.f;
            #pragma unroll 8
            for (int c = 0; c < 96; c++) s += qs[i][c] * ks[j][c];
        }
        E[((size_t)(b * NP + i * HW24 + w)) * 48 + j] = s;
    }
}

// ---------------- energies W + softmax (gamma!=0) ----------------
__global__ __launch_bounds__(256) void k_energyW(const unsigned short* __restrict__ VQK,
                                                 float* __restrict__ E, const float* __restrict__ gam) {
    if (gam[0] == 0.f) return;
    __shared__ float qs[24][97], ks[24][97], ew[24][24];
    const int b = blockIdx.x / HW24, h = blockIdx.x % HW24;
    const int tid = threadIdx.x;
    const int prow = b * NP + h * HW24;
    for (int idx = tid; idx < 24 * 12; idx += 256) {
        int i = idx / 12, c = (idx % 12) * 8;
        size_t base = ((size_t)(prow + i)) * NVQK + 768;
        s16x8 qv = *(const s16x8*)(VQK + base + c);
        s16x8 kv = *(const s16x8*)(VQK + base + 96 + c);
        #pragma unroll
        for (int u = 0; u < 8; u++) {
            qs[i][c + u] = bf2f((unsigned short)qv[u]);
            ks[i][c + u] = bf2f((unsigned short)kv[u]);
        }
    }
    __syncthreads();
    for (int idx = tid; idx < 576; idx += 256) {
        int i = idx / 24, j = idx - (idx / 24) * 24;
        float s = 0.f;
        #pragma unroll 8
        for (int c = 0; c < 96; c++) s += qs[i][c] * ks[j][c];
        ew[i][j] = s;
    }
    __syncthreads();
    if (tid < 24) {
        size_t p = prow + tid;
        float e[48];
        #pragma unroll
        for (int j = 0; j < 24; j++) e[j] = E[p * 48 + j];
        #pragma unroll
        for (int j = 0; j < 24; j++) e[24 + j] = ew[tid][j];
        float mx = NEGINF;
        #pragma unroll
        for (int j = 0; j < 48; j++) mx = fmaxf(mx, e[j]);
        float sum = 0.f;
        #pragma unroll
        for (int j = 0; j < 48; j++) { e[j] = __expf(e[j] - mx); sum += e[j]; }
        float inv = 1.f / sum;
        #pragma unroll
        for (int j = 0; j < 48; j++) E[p * 48 + j] = e[j] * inv;
    }
}

// ---------------- pass H (gamma!=0) ----------------
__global__ __launch_bounds__(192) void k_passH(const float* __restrict__ E,
        const unsigned short* __restrict__ VQK, const unsigned short* __restrict__ Y,
        const float* __restrict__ gamma, const float* __restrict__ pos,
        float* __restrict__ out) {
    const float g = gamma[0];
    if (g == 0.f) return;
    __shared__ float att[576];
    int bid = (blockIdx.x & 7) * 192 + (blockIdx.x >> 3);
    const int b = bid / HW24, w = bid % HW24;
    const int tid = threadIdx.x;
    for (int idx = tid; idx < 576; idx += 192) {
        int i = idx / 24, j = idx - (idx / 24) * 24;
        att[idx] = E[((size_t)(b * NP + i * HW24 + w)) * 48 + j];
    }
    __syncthreads();
    float vf[24][4];
    #pragma unroll
    for (int j = 0; j < 24; j++) {
        ushort4 vv = *(const ushort4*)(VQK + ((size_t)(b * NP + j * HW24 + w)) * NVQK + 4 * tid);
        vf[j][0] = bf2f(vv.x); vf[j][1] = bf2f(vv.y); vf[j][2] = bf2f(vv.z); vf[j][3] = bf2f(vv.w);
    }
    #pragma unroll
    for (int i = 0; i < 24; i++) {
        float a0 = 0.f, a1 = 0.f, a2 = 0.f, a3 = 0.f;
        #pragma unroll
        for (int j = 0; j < 24; j++) {
            float a = att[i * 24 + j];
            a0 += a * vf[j][0]; a1 += a * vf[j][1]; a2 += a * vf[j][2]; a3 += a * vf[j][3];
        }
        size_t p = (size_t)(b * NP + i * HW24 + w);
        ushort4 yv = *(const ushort4*)(Y + kp_addr((int)p, 4 * tid));
        float4 pv = *(const float4*)(pos + (size_t)(i * HW24 + w) * HID + 4 * tid);
        float4 o;
        o.x = g * a0 + bf2f(yv.x) + pv.x;
        o.y = g * a1 + bf2f(yv.y) + pv.y;
        o.z = g * a2 + bf2f(yv.z) + pv.z;
        o.w = g * a3 + bf2f(yv.w) + pv.w;
        *reinterpret_cast<float4*>(out + p * HID + 4 * tid) = o;
    }
}

// ---------------- pass W (gamma!=0) ----------------
__global__ __launch_bounds__(192) void k_passW(const float* __restrict__ E,
        const unsigned short* __restrict__ VQK, const float* __restrict__ gamma,
        float* __restrict__ out) {
    const float g = gamma[0];
    if (g == 0.f) return;
    __shared__ float att[576];
    int bid = (blockIdx.x & 7) * 192 + (blockIdx.x >> 3);
    const int b = bid / HW24, h = bid % HW24;
    const int tid = threadIdx.x;
    const int prow = b * NP + h * HW24;
    for (int idx = tid; idx < 576; idx += 192) {
        int i = idx / 24, j = idx - (idx / 24) * 24;
        att[idx] = E[((size_t)(prow + i)) * 48 + 24 + j];
    }
    __syncthreads();
    float vf[24][4];
    #pragma unroll
    for (int j = 0; j < 24; j++) {
        ushort4 vv = *(const ushort4*)(VQK + ((size_t)(prow + j)) * NVQK + 4 * tid);
        vf[j][0] = bf2f(vv.x); vf[j][1] = bf2f(vv.y); vf[j][2] = bf2f(vv.z); vf[j][3] = bf2f(vv.w);
    }
    #pragma unroll
    for (int i = 0; i < 24; i++) {
        float a0 = 0.f, a1 = 0.f, a2 = 0.f, a3 = 0.f;
        #pragma unroll
        for (int j = 0; j < 24; j++) {
            float a = att[i * 24 + j];
            a0 += a * vf[j][0]; a1 += a * vf[j][1]; a2 += a * vf[j][2]; a3 += a * vf[j][3];
        }
        size_t p = (size_t)(prow + i);
        float4 o = *reinterpret_cast<const float4*>(out + p * HID + 4 * tid);
        o.x += g * a0; o.y += g * a1; o.z += g * a2; o.w += g * a3;
        *reinterpret_cast<float4*>(out + p * HID + 4 * tid) = o;
    }
}

extern "C" void kernel_launch(void* const* d_in, const int* in_sizes, int n_in,
                              void* d_out, int out_size, void* d_ws, size_t ws_size,
                              hipStream_t stream) {
    const float* x       = (const float*)d_in[0];
    const float* patch_w = (const float*)d_in[1];
    const float* patch_b = (const float*)d_in[2];
    const float* wq      = (const float*)d_in[3];
    const float* bq      = (const float*)d_in[4];
    const float* wk      = (const float*)d_in[5];
    const float* bk      = (const float*)d_in[6];
    const float* wv      = (const float*)d_in[7];
    const float* bv      = (const float*)d_in[8];
    const float* gamma   = (const float*)d_in[9];
    const float* pos_emb = (const float*)d_in[10];
    float* out = (float*)d_out;

    hipFuncSetAttribute(reinterpret_cast<const void*>(k_gemmFused),
                        hipFuncAttributeMaxDynamicSharedMemorySize, 131072);
    hipFuncSetAttribute(reinterpret_cast<const void*>(k_gemm256),
                        hipFuncAttributeMaxDynamicSharedMemorySize, 163840);

    char* ws = (char*)d_ws;
    size_t off = 0;
    auto alloc = [&](size_t bytes) { char* pp = ws + off; off += (bytes + 255) & ~(size_t)255; return pp; };
    unsigned short* VQK = (unsigned short*)alloc((size_t)MROWS * NVQK * 2);
    unsigned short* Y   = (unsigned short*)alloc((size_t)MROWS * HID * 2);  // K-packed (gamma!=0 path)
    unsigned short* Wp  = (unsigned short*)alloc((size_t)HID * HID * 2);
    unsigned short* Wvqk= (unsigned short*)alloc((size_t)NVQK * HID * 2);
    float*          Bvqk= (float*)alloc(NVQK * 4);
    float*          E   = (float*)alloc((size_t)MROWS * 48 * 4);

    k_prep<<<dim3((NVQK * HID + 255) / 256), dim3(256), 0, stream>>>(patch_w, wq, wk, wv, bq, bk, bv, Wp, Wvqk, Bvqk);
    // fused im2col + patch GEMM; gamma==0 -> out = y + pos directly (f32)
    k_gemmFused<<<dim3((MROWS / 256) * (HID / 256)), dim3(512), 131072, stream>>>(
        x, Wp, patch_b, Y, out, pos_emb, gamma);
    // ---- gamma!=0 full path (all guarded; no-ops for gamma==0) ----
    k_gemm256<<<dim3((MROWS / 256) * (NVQK / 256)), dim3(512), 163840, stream>>>(
        Y, Wvqk, Bvqk, VQK, gamma, NVQK / 256);
    k_energyH<<<dim3(BATCH * HW24), dim3(256), 0, stream>>>(VQK, E, gamma);
    k_energyW<<<dim3(BATCH * HW24), dim3(256), 0, stream>>>(VQK, E, gamma);
    k_passH<<<dim3(BATCH * HW24), dim3(192), 0, stream>>>(E, VQK, Y, gamma, pos_emb, out);
    k_passW<<<dim3(BATCH * HW24), dim3(192), 0, stream>>>(E, VQK, gamma, out);
}